// Round 8
// baseline (3522.663 us; speedup 1.0000x reference)
//
#include <hip/hip_runtime.h>
#include <cstdint>
#include <cstddef>

typedef __bf16 bf16x8 __attribute__((ext_vector_type(8)));
typedef float f32x4 __attribute__((ext_vector_type(4)));

#define HD 256
#define TLEN 1000
#define NSTEP 999
#define BTILE 4

// ws layout (bf16 elements): W1R | W2R | W3R | W4R, fragment-ordered (r4 layout)
#define W1R_OFF 0
#define W2R_OFF 16384
#define W3R_OFF 81920
#define W4R_OFF 147456
#define WS_ELEMS 151552

__device__ __forceinline__ void wg_barrier() {
  // LDS-only drain + barrier: do NOT force vmcnt(0) like __syncthreads does,
  // so the z-prefetch / out-stores stay in flight across layer barriers.
  asm volatile("s_waitcnt lgkmcnt(0)\n\ts_barrier" ::: "memory");
}

// Repack fp32 weights -> bf16 MFMA A-fragments in ws (r4 layout, unchanged).
// Fragment element for (w,kb,tt,lane,j): k = kb*32 + (lane>>4)*8 + j ; n = w*32 + tt*16 + (lane&15)
// value = W[k][n] (b1 folded into W1 padded row k==48).
__global__ void prep_weights(const float* __restrict__ W1, const float* __restrict__ b1,
                             const float* __restrict__ W2, const float* __restrict__ W3,
                             const float* __restrict__ W4, __bf16* __restrict__ ws) {
  int tid = blockIdx.x * blockDim.x + threadIdx.x;
  if (tid >= WS_ELEMS) return;
  float val = 0.0f;
  if (tid < W2R_OFF) {                       // W1R: 8w x 2kb x 2tt x 64lane x 8j
    int t = tid;
    int j = t & 7, lane = (t >> 3) & 63, tt = (t >> 9) & 1, kb = (t >> 10) & 1, w = (t >> 11) & 7;
    int k = kb * 32 + ((lane >> 4) * 8) + j;
    int n = w * 32 + tt * 16 + (lane & 15);
    if (k < 48) val = W1[k * HD + n];
    else if (k == 48) val = b1[n];           // bias folded via constant-1 input at k=48
  } else if (tid < W3R_OFF) {                // W2R: 8w x 8kb x 2tt x 64 x 8
    int t = tid - W2R_OFF;
    int j = t & 7, lane = (t >> 3) & 63, tt = (t >> 9) & 1, kb = (t >> 10) & 7, w = (t >> 13) & 7;
    int k = kb * 32 + ((lane >> 4) * 8) + j;
    int n = w * 32 + tt * 16 + (lane & 15);
    val = W2[k * HD + n];
  } else if (tid < W4R_OFF) {                // W3R
    int t = tid - W3R_OFF;
    int j = t & 7, lane = (t >> 3) & 63, tt = (t >> 9) & 1, kb = (t >> 10) & 7, w = (t >> 13) & 7;
    int k = kb * 32 + ((lane >> 4) * 8) + j;
    int n = w * 32 + tt * 16 + (lane & 15);
    val = W3[k * HD + n];
  } else {                                   // W4R: 8kb x 64 x 8, N padded 8->16 with zeros
    int t = tid - W4R_OFF;
    int j = t & 7, lane = (t >> 3) & 63, kb = (t >> 9) & 7;
    int k = kb * 32 + ((lane >> 4) * 8) + j;
    int n = lane & 15;
    val = (n < 8) ? W4[k * 8 + n] : 0.0f;
  }
  ws[tid] = (__bf16)val;
}

// r7 post-mortem: r5/r6/r7 all died of REGISTER SPILL (WRITE/FETCH growth is
// the tell), not of their structural ideas. This version = r4 champion with
// the two ideas re-applied INSIDE the register envelope (weight set identical
// to r4: w1f[2][2] + w2f + w3f + single w4f = 148 regs, AGPR-parked):
//  (A) layer MFMA chains split 8 -> 4+4 (expose less MFMA latency; r4's
//      MfmaUtil cycles = 16.4/MFMA, issue rate is ~5)
//  (D) phase 4 merged into phase 1: all waves redundantly reduce p4 (8 masked
//      16B LDS reads), x state in q0/q1 lane registers, L1 frag built via two
//      shfl_xor rounds, z_eff from per-lane prefetched registers (q1/q3).
//      Deletes barrier 4, the serial wave-0 section, and the x/z LDS round trip.
__global__ __launch_bounds__(512, 2) void ode_main(
    const float* __restrict__ t_g, const float* __restrict__ x_g,
    const float* __restrict__ z_g, const float* __restrict__ ev_g,
    const float* __restrict__ zj_g, const float* __restrict__ b2_g,
    const float* __restrict__ b3_g, const float* __restrict__ b4_g,
    const __bf16* __restrict__ ws, float* __restrict__ out) {
  __shared__ __align__(16) __bf16 h_a[16 * 264];   // 16 rows kept (4 live), row 528B
  __shared__ __align__(16) __bf16 h_b[16 * 264];
  __shared__ __align__(16) float p4[8 * 128];      // [wave][bcol*8 + q*4 .. +3]
  __shared__ __align__(16) float x0s[16 * 12];     // init-time staging (const after)
  __shared__ __align__(16) float z0s[16 * 12];

  const int tid  = threadIdx.x;
  const int lane = tid & 63;
  const int wid  = tid >> 6;     // 8 waves; wave w owns hidden cols [32w, 32w+32)
  const int bcol = lane & 15;    // B/C-operand column; batch row if < BTILE
  const int q    = lane >> 4;    // quad
  const int b0   = blockIdx.x * BTILE;
  const bool live = bcol < BTILE;
  const size_t gb = (size_t)(b0 + (live ? bcol : 0));  // masked use only

  // ---- stage x0/z0 (rows >= BTILE zeroed) + zero p4 ----
  if (tid < 192) {
    int m = tid / 12, d = tid % 12;
    float xv = 0.f, zv = 0.f;
    if (m < BTILE && d < 8) {
      size_t g = (size_t)(b0 + m);
      xv = x_g[g * (TLEN * 8) + d];
      zv = z_g[g * (TLEN * 8) + d];
    }
    x0s[m * 12 + d] = xv;
    z0s[m * 12 + d] = zv;
  }
  if (tid < 512) { p4[tid] = 0.f; if (tid < 512) { int t2 = tid + 512; if (t2 < 1024) p4[t2] = 0.f; } }
  __syncthreads();

  // ---- resident weight fragments (r4 set, AGPR-parked by the compiler) ----
  const bf16x8* wsv = (const bf16x8*)ws;
  bf16x8 w1f[2][2], w2f[8][2], w3f[8][2];
#pragma unroll
  for (int kb = 0; kb < 2; ++kb)
#pragma unroll
    for (int tt = 0; tt < 2; ++tt)
      w1f[kb][tt] = wsv[(W1R_OFF / 8) + ((wid * 2 + kb) * 2 + tt) * 64 + lane];
#pragma unroll
  for (int kb = 0; kb < 8; ++kb)
#pragma unroll
    for (int tt = 0; tt < 2; ++tt) {
      w2f[kb][tt] = wsv[(W2R_OFF / 8) + ((wid * 8 + kb) * 2 + tt) * 64 + lane];
      w3f[kb][tt] = wsv[(W3R_OFF / 8) + ((wid * 8 + kb) * 2 + tt) * 64 + lane];
    }
  bf16x8 w4f = wsv[(W4R_OFF / 8) + wid * 64 + lane];  // W4 k-slice for this wave only

  // biases as C-init: lane's 4 C rows are hidden n = wid*32 + tt*16 + q*4 + e
  f32x4 b2v[2], b3v[2];
#pragma unroll
  for (int tt = 0; tt < 2; ++tt) {
    int n0 = wid * 32 + tt * 16 + q * 4;
    b2v[tt] = *(const f32x4*)(b2_g + n0);
    b3v[tt] = *(const f32x4*)(b3_g + n0);
  }
  f32x4 b4v = {0.f, 0.f, 0.f, 0.f};
  if (q < 2) b4v = *(const f32x4*)(b4_g + q * 4);   // live out dims on q<2 lanes

  // layer-1 constants (r4): a0c = x0 (q even) / z0 (q odd); sub = same in f32
  f32x4 sub0, sub1;
  bf16x8 a0c;
  {
    const float* base = ((q & 1) ? z0s : x0s) + bcol * 12;
    f32x4 r0 = *(const f32x4*)(base);
    f32x4 r1 = *(const f32x4*)(base + 4);
    sub0 = r0; sub1 = r1;
#pragma unroll
    for (int e = 0; e < 4; ++e) { a0c[e] = (__bf16)r0[e]; a0c[e + 4] = (__bf16)r1[e]; }
  }
  bf16x8 zf;
#pragma unroll
  for (int e = 0; e < 8; ++e) zf[e] = (__bf16)0.f;
  bf16x8 k48f = zf;
  k48f[0] = (__bf16)1.0f;  // constant-1 input at padded k=48 -> adds b1

  // per-lane x state: q0 holds dims 0-3, q1 holds dims 4-7 of batch bcol
  f32x4 x4 = {0.f, 0.f, 0.f, 0.f};
  if (q < 2) x4 = *(const f32x4*)(x0s + bcol * 12 + q * 4);

  // z personals on q1/q3 lanes: event, z_jump, prefetched z(:, i)
  float ev1 = 0.f;
  f32x4 zjA = {0.f, 0.f, 0.f, 0.f}, zjB = {0.f, 0.f, 0.f, 0.f};
  f32x4 zpA = {0.f, 0.f, 0.f, 0.f}, zpB = {0.f, 0.f, 0.f, 0.f};
  if ((q & 1) && live) {
    ev1 = ev_g[gb];
    zjA = *(const f32x4*)(zj_g + gb * 8);
    zjB = *(const f32x4*)(zj_g + gb * 8 + 4);
    zpA = *(const f32x4*)(z_g + gb * (TLEN * 8));      // z(:, 0)
    zpB = *(const f32x4*)(z_g + gb * (TLEN * 8) + 4);
  }

  // persistent masked-read destinations: dead lanes keep zeros forever.
  bf16x8 bfr[8];
#pragma unroll
  for (int kb = 0; kb < 8; ++kb) bfr[kb] = zf;
  bf16x8 h4r = zf;

  auto layer = [&](const __bf16* src, __bf16* dst, const bf16x8 (*wf)[2], const f32x4* bv) {
    const bf16x8* hp = (const bf16x8*)src;
    if (live) {   // masked reads: dead lanes generate no LDS traffic (r4-proven)
#pragma unroll
      for (int kb = 0; kb < 8; ++kb) bfr[kb] = hp[bcol * 33 + kb * 4 + q];  // ds_read_b128 x8
    }
#pragma unroll
    for (int tt = 0; tt < 2; ++tt) {
      f32x4 c0 = bv[tt];
      f32x4 c1 = {0.f, 0.f, 0.f, 0.f};
      // (A) two independent 4-chains per tt -> 4 chains in flight per wave
#pragma unroll
      for (int kb = 0; kb < 4; ++kb)
        c0 = __builtin_amdgcn_mfma_f32_16x16x32_bf16(wf[kb][tt], bfr[kb], c0, 0, 0, 0);
#pragma unroll
      for (int kb = 4; kb < 8; ++kb)
        c1 = __builtin_amdgcn_mfma_f32_16x16x32_bf16(wf[kb][tt], bfr[kb], c1, 0, 0, 0);
      union { __bf16 h4[4]; unsigned long long u; } pk;
#pragma unroll
      for (int e = 0; e < 4; ++e) {
        float v = c0[e] + c1[e];
        v = (v > 0.f) ? v : (__expf(v) - 1.0f);  // ELU
        pk.h4[e] = (__bf16)v;
      }
      if (live)
        *(unsigned long long*)(dst + bcol * 264 + wid * 32 + tt * 16 + q * 4) = pk.u;
    }
  };

  float tc = t_g[0];
  float tn_hold = tc;
  __syncthreads();

#pragma unroll 1
  for (int i = 0; i <= NSTEP; ++i) {
    // ---- phase A: finish step i-1 (all-wave p4 reduce -> x) + start step i (L1) ----
    float tn = tn_hold;
    float dt = tn - tc;
    tc = tn;
    if (q < 2 && live) {
      const float* pp = p4 + bcol * 8 + q * 4;
      f32x4 a0 = *(const f32x4*)(pp + 0 * 128);
      f32x4 a1 = *(const f32x4*)(pp + 1 * 128);
      f32x4 a2 = *(const f32x4*)(pp + 2 * 128);
      f32x4 a3 = *(const f32x4*)(pp + 3 * 128);
      f32x4 a4 = *(const f32x4*)(pp + 4 * 128);
      f32x4 a5 = *(const f32x4*)(pp + 5 * 128);
      f32x4 a6 = *(const f32x4*)(pp + 6 * 128);
      f32x4 a7 = *(const f32x4*)(pp + 7 * 128);
      f32x4 s = ((a0 + a1) + (a2 + a3)) + ((a4 + a5) + (a6 + a7));
#pragma unroll
      for (int e = 0; e < 4; ++e) x4[e] += dt * (s[e] + b4v[e]);   // x_i (dt=0 at i=0)
      if (wid == 0)   // fire-and-forget; wg_barrier never drains vmcnt
        *(f32x4*)(out + gb * (TLEN * 8) + (size_t)i * 8 + q * 4) = x4;
    }
    if (i == NSTEP) break;   // uniform exit after storing out[:, NSTEP]

    // full-x exchange: q0/q1 swap halves (xor16), then forward to q2/q3 (xor32)
    f32x4 o4, lo, hi, xlo, xhi;
#pragma unroll
    for (int e = 0; e < 4; ++e) o4[e] = __shfl_xor(x4[e], 16);
#pragma unroll
    for (int e = 0; e < 4; ++e) {
      lo[e] = (q & 1) ? o4[e] : x4[e];   // dims 0-3
      hi[e] = (q & 1) ? x4[e] : o4[e];   // dims 4-7
    }
#pragma unroll
    for (int e = 0; e < 4; ++e) {
      float l2 = __shfl_xor(lo[e], 32);
      float h2 = __shfl_xor(hi[e], 32);
      xlo[e] = (q >= 2) ? l2 : lo[e];
      xhi[e] = (q >= 2) ? h2 : hi[e];
    }
    // z_eff(i) on q1/q3 lanes (prefetched z + event select); zeros elsewhere
    bool jmp = (tn >= ev1);
    f32x4 zelo, zehi;
#pragma unroll
    for (int e = 0; e < 4; ++e) {
      zelo[e] = jmp ? zjA[e] : zpA[e];
      zehi[e] = jmp ? zjB[e] : zpB[e];
    }
    // layer-1 B-frags (r4 mapping): q0:(x0 | x) q1:(z0 | z_eff) q2:(x-x0 | k48) q3:(z_eff-z0 | 0)
    bf16x8 f0, f1;
    if (q == 0) {
      f0 = a0c;
#pragma unroll
      for (int e = 0; e < 4; ++e) { f1[e] = (__bf16)xlo[e]; f1[e + 4] = (__bf16)xhi[e]; }
    } else if (q == 1) {
      f0 = a0c;
#pragma unroll
      for (int e = 0; e < 4; ++e) { f1[e] = (__bf16)zelo[e]; f1[e + 4] = (__bf16)zehi[e]; }
    } else if (q == 2) {
#pragma unroll
      for (int e = 0; e < 4; ++e) {
        f0[e] = (__bf16)(xlo[e] - sub0[e]);
        f0[e + 4] = (__bf16)(xhi[e] - sub1[e]);
      }
      f1 = k48f;
    } else {
#pragma unroll
      for (int e = 0; e < 4; ++e) {
        f0[e] = (__bf16)(zelo[e] - sub0[e]);
        f0[e + 4] = (__bf16)(zehi[e] - sub1[e]);
      }
      f1 = zf;
    }
#pragma unroll
    for (int tt = 0; tt < 2; ++tt) {
      f32x4 c = {0.f, 0.f, 0.f, 0.f};
      c = __builtin_amdgcn_mfma_f32_16x16x32_bf16(w1f[0][tt], f0, c, 0, 0, 0);
      c = __builtin_amdgcn_mfma_f32_16x16x32_bf16(w1f[1][tt], f1, c, 0, 0, 0);
      union { __bf16 h4[4]; unsigned long long u; } pk;
#pragma unroll
      for (int e = 0; e < 4; ++e) {
        float v = c[e];
        v = (v > 0.f) ? v : (__expf(v) - 1.0f);
        pk.h4[e] = (__bf16)v;
      }
      if (live)
        *(unsigned long long*)(h_a + bcol * 264 + wid * 32 + tt * 16 + q * 4) = pk.u;
    }
    wg_barrier();

    // ---- phase B: layer 2; prefetch z(:, i+1) + t(i+1) under it ----
    if ((q & 1) && live) {
      zpA = *(const f32x4*)(z_g + gb * (TLEN * 8) + (size_t)(i + 1) * 8);
      zpB = *(const f32x4*)(z_g + gb * (TLEN * 8) + (size_t)(i + 1) * 8 + 4);
    }
    tn_hold = t_g[i + 1];
    layer(h_a, h_b, w2f, b2v);
    wg_barrier();

    // ---- phase C: layer 3 (-> h_a) + fused W4 partial on OWN 32 cols -> p4 ----
    layer(h_b, h_a, w3f, b3v);
    {
      if (live) h4r = ((const bf16x8*)h_a)[bcol * 33 + wid * 4 + q];  // same-wave RAW
      f32x4 c = {0.f, 0.f, 0.f, 0.f};
      c = __builtin_amdgcn_mfma_f32_16x16x32_bf16(w4f, h4r, c, 0, 0, 0);
      if (q < 2 && live)
        *(f32x4*)(p4 + wid * 128 + bcol * 8 + q * 4) = c;
    }
    wg_barrier();
  }
}

extern "C" void kernel_launch(void* const* d_in, const int* in_sizes, int n_in,
                              void* d_out, int out_size, void* d_ws, size_t ws_size,
                              hipStream_t stream) {
  const float* t  = (const float*)d_in[0];
  const float* x  = (const float*)d_in[1];
  const float* z  = (const float*)d_in[2];
  const float* ev = (const float*)d_in[3];
  const float* zj = (const float*)d_in[4];
  const float* W1 = (const float*)d_in[5];
  const float* b1 = (const float*)d_in[6];
  const float* W2 = (const float*)d_in[7];
  const float* b2 = (const float*)d_in[8];
  const float* W3 = (const float*)d_in[9];
  const float* b3 = (const float*)d_in[10];
  const float* W4 = (const float*)d_in[11];
  const float* b4 = (const float*)d_in[12];
  __bf16* ws = (__bf16*)d_ws;
  float* out = (float*)d_out;

  prep_weights<<<592, 256, 0, stream>>>(W1, b1, W2, W3, W4, ws);
  ode_main<<<256, 512, 0, stream>>>(t, x, z, ev, zj, b2, b3, b4, ws, out);
}

// Round 10
// 2906.354 us; speedup vs baseline: 1.2121x; 1.2121x over previous
//
#include <hip/hip_runtime.h>
#include <cstdint>
#include <cstddef>

typedef __bf16 bf16x8 __attribute__((ext_vector_type(8)));
typedef float f32x4 __attribute__((ext_vector_type(4)));

#define HD 256
#define TLEN 1000
#define NSTEP 999
#define BTILE 4

// ws layout (bf16 elements): W1R | W2R | W3R | W4R, fragment-ordered (r4 layout)
#define W1R_OFF 0
#define W2R_OFF 16384
#define W3R_OFF 81920
#define W4R_OFF 147456
#define WS_ELEMS 151552

__device__ __forceinline__ void wg_barrier() {
  // LDS-only drain + barrier: do NOT force vmcnt(0) like __syncthreads does,
  // so the z-prefetch / out-stores stay in flight across layer barriers.
  asm volatile("s_waitcnt lgkmcnt(0)\n\ts_barrier" ::: "memory");
}

// Repack fp32 weights -> bf16 MFMA A-fragments in ws (r4 layout, unchanged).
// Fragment element for (w,kb,tt,lane,j): k = kb*32 + (lane>>4)*8 + j ; n = w*32 + tt*16 + (lane&15)
// value = W[k][n] (b1 folded into W1 padded row k==48).
__global__ void prep_weights(const float* __restrict__ W1, const float* __restrict__ b1,
                             const float* __restrict__ W2, const float* __restrict__ W3,
                             const float* __restrict__ W4, __bf16* __restrict__ ws) {
  int tid = blockIdx.x * blockDim.x + threadIdx.x;
  if (tid >= WS_ELEMS) return;
  float val = 0.0f;
  if (tid < W2R_OFF) {                       // W1R: 8w x 2kb x 2tt x 64lane x 8j
    int t = tid;
    int j = t & 7, lane = (t >> 3) & 63, tt = (t >> 9) & 1, kb = (t >> 10) & 1, w = (t >> 11) & 7;
    int k = kb * 32 + ((lane >> 4) * 8) + j;
    int n = w * 32 + tt * 16 + (lane & 15);
    if (k < 48) val = W1[k * HD + n];
    else if (k == 48) val = b1[n];           // bias folded via constant-1 input at k=48
  } else if (tid < W3R_OFF) {                // W2R: 8w x 8kb x 2tt x 64 x 8
    int t = tid - W2R_OFF;
    int j = t & 7, lane = (t >> 3) & 63, tt = (t >> 9) & 1, kb = (t >> 10) & 7, w = (t >> 13) & 7;
    int k = kb * 32 + ((lane >> 4) * 8) + j;
    int n = w * 32 + tt * 16 + (lane & 15);
    val = W2[k * HD + n];
  } else if (tid < W4R_OFF) {                // W3R
    int t = tid - W3R_OFF;
    int j = t & 7, lane = (t >> 3) & 63, tt = (t >> 9) & 1, kb = (t >> 10) & 7, w = (t >> 13) & 7;
    int k = kb * 32 + ((lane >> 4) * 8) + j;
    int n = w * 32 + tt * 16 + (lane & 15);
    val = W3[k * HD + n];
  } else {                                   // W4R: 8kb x 64 x 8, N padded 8->16 with zeros
    int t = tid - W4R_OFF;
    int j = t & 7, lane = (t >> 3) & 63, kb = (t >> 9) & 7;
    int k = kb * 32 + ((lane >> 4) * 8) + j;
    int n = lane & 15;
    val = (n < 8) ? W4[k * 8 + n] : 0.0f;
  }
  ws[tid] = (__bf16)val;
}

// (D-lite), resubmitted after infra failure: barrier-4 removal register-dieted
// to NET -1 persistent regs vs r4:
//  - x in q0/q1 lane registers; ALL waves redundantly reduce p4 (masked 16B
//    reads); 3x shfl_xor distributes x to frag quads. No x LDS round trip,
//    no wave-0 serial section, 3 barriers/step.
//  - z_eff stays in LDS, produced by wave 2 (r4 code) but in PHASE B: write
//    is 1 barrier after current-step reads (WAR ok) and 2 barriers before
//    next-step reads (RAW ok). Deletes r8's 16-reg z-personal block.
//  - a0c/k48f persistence dropped (rebuilt per step), b4l -> b4v.
//  - (A) layer MFMA chains split 4+4 (transient only).
__global__ __launch_bounds__(512, 2) void ode_main(
    const float* __restrict__ t_g, const float* __restrict__ x_g,
    const float* __restrict__ z_g, const float* __restrict__ ev_g,
    const float* __restrict__ zj_g, const float* __restrict__ b2_g,
    const float* __restrict__ b3_g, const float* __restrict__ b4_g,
    const __bf16* __restrict__ ws, float* __restrict__ out) {
  __shared__ __align__(16) __bf16 h_a[16 * 264];   // 16 rows kept (4 live), row 528B
  __shared__ __align__(16) __bf16 h_b[16 * 264];
  __shared__ __align__(16) float p4[8 * 128];      // [wave][bcol*8 + q*4 .. +3]
  __shared__ __align__(16) float z_eff[16 * 12];
  __shared__ __align__(16) float x0s[16 * 12];
  __shared__ __align__(16) float z0s[16 * 12];
  __shared__ __align__(16) float zjs[16 * 12];
  __shared__ float evs[16];

  const int tid  = threadIdx.x;
  const int lane = tid & 63;
  const int wid  = tid >> 6;     // 8 waves; wave w owns hidden cols [32w, 32w+32)
  const int bcol = lane & 15;    // B/C-operand column; batch row if < BTILE
  const int q    = lane >> 4;    // quad
  const int b0   = blockIdx.x * BTILE;
  const bool live = bcol < BTILE;
  const size_t gb = (size_t)(b0 + (live ? bcol : 0));  // masked use only

  // ---- stage per-batch constants (rows >= BTILE zeroed) + zero p4 ----
  if (tid < 128) {
    int m = tid >> 3, d = tid & 7;
    if (m < BTILE) {
      size_t g = (size_t)(b0 + m);
      x0s[m * 12 + d] = x_g[g * (TLEN * 8) + d];
      z0s[m * 12 + d] = z_g[g * (TLEN * 8) + d];
      zjs[m * 12 + d] = zj_g[g * 8 + d];
      if (d == 0) evs[m] = ev_g[g];
    } else {
      x0s[m * 12 + d] = 0.f;
      z0s[m * 12 + d] = 0.f;
      zjs[m * 12 + d] = 0.f;
      if (d == 0) evs[m] = 0.f;
    }
  }
  if (tid < 512) { p4[tid] = 0.f; p4[tid + 512] = 0.f; }
  __syncthreads();

  if (tid < 128) {  // z_eff for step 0 (rows >= BTILE resolve to 0)
    int m = tid >> 3, d = tid & 7;
    float t0 = t_g[0];
    z_eff[m * 12 + d] = (t0 >= evs[m]) ? zjs[m * 12 + d] : z0s[m * 12 + d];
  }

  // ---- resident weight fragments (r4 set, byte-identical) ----
  const bf16x8* wsv = (const bf16x8*)ws;
  bf16x8 w1f[2][2], w2f[8][2], w3f[8][2];
#pragma unroll
  for (int kb = 0; kb < 2; ++kb)
#pragma unroll
    for (int tt = 0; tt < 2; ++tt)
      w1f[kb][tt] = wsv[(W1R_OFF / 8) + ((wid * 2 + kb) * 2 + tt) * 64 + lane];
#pragma unroll
  for (int kb = 0; kb < 8; ++kb)
#pragma unroll
    for (int tt = 0; tt < 2; ++tt) {
      w2f[kb][tt] = wsv[(W2R_OFF / 8) + ((wid * 8 + kb) * 2 + tt) * 64 + lane];
      w3f[kb][tt] = wsv[(W3R_OFF / 8) + ((wid * 8 + kb) * 2 + tt) * 64 + lane];
    }
  bf16x8 w4f = wsv[(W4R_OFF / 8) + wid * 64 + lane];  // W4 k-slice for this wave

  // biases as C-init: lane's 4 C rows are hidden n = wid*32 + tt*16 + q*4 + e
  f32x4 b2v[2], b3v[2];
#pragma unroll
  for (int tt = 0; tt < 2; ++tt) {
    int n0 = wid * 32 + tt * 16 + q * 4;
    b2v[tt] = *(const f32x4*)(b2_g + n0);
    b3v[tt] = *(const f32x4*)(b3_g + n0);
  }
  f32x4 b4v = {0.f, 0.f, 0.f, 0.f};
  if (q < 2) b4v = *(const f32x4*)(b4_g + q * 4);   // live out dims on q<2 lanes

  // wave-2 personals (z_eff producer, r4): lanes 0..15 cover (m 0..3) x (d pairs)
  const int m1 = lane >> 2;
  const int d0 = (lane & 3) * 2;
  float2 zjf = make_float2(0.f, 0.f);
  float ev1 = 0.f;
  const bool zprod = (wid == 2) && (lane < BTILE * 4);
  if (zprod) {
    zjf.x = zjs[m1 * 12 + d0];
    zjf.y = zjs[m1 * 12 + d0 + 1];
    ev1 = evs[m1];
  }

  // layer-1 constants: sub = x0 (q even) / z0 (q odd) in f32 (a0c rebuilt per step)
  f32x4 sub0, sub1;
  {
    const float* base = ((q & 1) ? z0s : x0s) + bcol * 12;
    sub0 = *(const f32x4*)(base);
    sub1 = *(const f32x4*)(base + 4);
  }
  bf16x8 zf;
#pragma unroll
  for (int e = 0; e < 8; ++e) zf[e] = (__bf16)0.f;

  // per-lane x state: q0 holds dims 0-3, q1 holds dims 4-7 of batch bcol
  f32x4 x4 = {0.f, 0.f, 0.f, 0.f};
  if (q < 2) x4 = *(const f32x4*)(x0s + bcol * 12 + q * 4);

  // persistent masked-read destinations: dead lanes keep zeros forever.
  bf16x8 bfr[8];
#pragma unroll
  for (int kb = 0; kb < 8; ++kb) bfr[kb] = zf;
  bf16x8 h4r = zf;

  auto layer = [&](const __bf16* src, __bf16* dst, const bf16x8 (*wf)[2], const f32x4* bv) {
    const bf16x8* hp = (const bf16x8*)src;
    if (live) {   // masked reads: dead lanes generate no LDS traffic (r4-proven)
#pragma unroll
      for (int kb = 0; kb < 8; ++kb) bfr[kb] = hp[bcol * 33 + kb * 4 + q];  // ds_read_b128 x8
    }
#pragma unroll
    for (int tt = 0; tt < 2; ++tt) {
      f32x4 c0 = bv[tt];
      f32x4 c1 = {0.f, 0.f, 0.f, 0.f};
      // (A) two independent 4-chains per tt
#pragma unroll
      for (int kb = 0; kb < 4; ++kb)
        c0 = __builtin_amdgcn_mfma_f32_16x16x32_bf16(wf[kb][tt], bfr[kb], c0, 0, 0, 0);
#pragma unroll
      for (int kb = 4; kb < 8; ++kb)
        c1 = __builtin_amdgcn_mfma_f32_16x16x32_bf16(wf[kb][tt], bfr[kb], c1, 0, 0, 0);
      union { __bf16 h4[4]; unsigned long long u; } pk;
#pragma unroll
      for (int e = 0; e < 4; ++e) {
        float v = c0[e] + c1[e];
        v = (v > 0.f) ? v : (__expf(v) - 1.0f);  // ELU
        pk.h4[e] = (__bf16)v;
      }
      if (live)
        *(unsigned long long*)(dst + bcol * 264 + wid * 32 + tt * 16 + q * 4) = pk.u;
    }
  };

  float tc = t_g[0];
  float tn_hold = tc;
  __syncthreads();

#pragma unroll 1
  for (int i = 0; i <= NSTEP; ++i) {
    // ---- phase A: finish step i-1 (all-wave p4 reduce -> x regs) + L1 of step i ----
    float tn = tn_hold;
    float dt = tn - tc;   // dt = 0 at i = 0
    tc = tn;
    if (q < 2 && live) {
      const float* pp = p4 + bcol * 8 + q * 4;
      f32x4 a0 = *(const f32x4*)(pp + 0 * 128);
      f32x4 a1 = *(const f32x4*)(pp + 1 * 128);
      f32x4 a2 = *(const f32x4*)(pp + 2 * 128);
      f32x4 a3 = *(const f32x4*)(pp + 3 * 128);
      f32x4 a4 = *(const f32x4*)(pp + 4 * 128);
      f32x4 a5 = *(const f32x4*)(pp + 5 * 128);
      f32x4 a6 = *(const f32x4*)(pp + 6 * 128);
      f32x4 a7 = *(const f32x4*)(pp + 7 * 128);
      f32x4 s = ((a0 + a1) + (a2 + a3)) + ((a4 + a5) + (a6 + a7));
#pragma unroll
      for (int e = 0; e < 4; ++e) x4[e] += dt * (s[e] + b4v[e]);
      if (wid == 0)   // fire-and-forget; wg_barrier never drains vmcnt
        *(f32x4*)(out + gb * (TLEN * 8) + (size_t)i * 8 + q * 4) = x4;
    }
    if (i == NSTEP) break;   // uniform exit after storing out[:, NSTEP]

    float2 zpre = make_float2(0.f, 0.f);
    if (zprod)  // prefetch z[:, i+1]; consumed by wave 2 in phase B
      zpre = *(const float2*)(z_g + ((size_t)(b0 + m1) * TLEN + (i + 1)) * 8 + d0);

    // distribute x: s16 (q0<->q1), s32 (q0->q2), s48 (q1->q2)
    f32x4 s16, s32, s48;
#pragma unroll
    for (int e = 0; e < 4; ++e) {
      s16[e] = __shfl_xor(x4[e], 16);
      s32[e] = __shfl_xor(x4[e], 32);
      s48[e] = __shfl_xor(x4[e], 48);
    }
    // a0c = bf16(sub) rebuilt (q even: x0, q odd: z0)
    bf16x8 a0c;
#pragma unroll
    for (int e = 0; e < 4; ++e) { a0c[e] = (__bf16)sub0[e]; a0c[e + 4] = (__bf16)sub1[e]; }

    // layer-1 B-frags (r4 k-mapping):
    // q0: f0 = x0,        f1 = x            (k 0-7   | k 32-39)
    // q1: f0 = z0,        f1 = z_eff        (k 8-15  | k 40-47)
    // q2: f0 = x - x0,    f1 = k48 const-1  (k 16-23 | k 48-55)
    // q3: f0 = z_eff - z0,f1 = 0            (k 24-31 | k 56-63)
    bf16x8 f0, f1;
    if (q == 0) {
      f0 = a0c;
#pragma unroll
      for (int e = 0; e < 4; ++e) { f1[e] = (__bf16)x4[e]; f1[e + 4] = (__bf16)s16[e]; }
    } else if (q == 1) {
      const float* rp = z_eff + bcol * 12;
      f32x4 r0 = *(const f32x4*)(rp);
      f32x4 r1 = *(const f32x4*)(rp + 4);
      f0 = a0c;
#pragma unroll
      for (int e = 0; e < 4; ++e) { f1[e] = (__bf16)r0[e]; f1[e + 4] = (__bf16)r1[e]; }
    } else if (q == 2) {
#pragma unroll
      for (int e = 0; e < 4; ++e) {
        f0[e] = (__bf16)(s32[e] - sub0[e]);
        f0[e + 4] = (__bf16)(s48[e] - sub1[e]);
      }
      f1 = zf;
      f1[0] = (__bf16)1.0f;   // constant-1 at padded k=48 -> adds b1
    } else {
      const float* rp = z_eff + bcol * 12;
      f32x4 r0 = *(const f32x4*)(rp);
      f32x4 r1 = *(const f32x4*)(rp + 4);
#pragma unroll
      for (int e = 0; e < 4; ++e) {
        f0[e] = (__bf16)(r0[e] - sub0[e]);
        f0[e + 4] = (__bf16)(r1[e] - sub1[e]);
      }
      f1 = zf;
    }
#pragma unroll
    for (int tt = 0; tt < 2; ++tt) {
      f32x4 c = {0.f, 0.f, 0.f, 0.f};
      c = __builtin_amdgcn_mfma_f32_16x16x32_bf16(w1f[0][tt], f0, c, 0, 0, 0);
      c = __builtin_amdgcn_mfma_f32_16x16x32_bf16(w1f[1][tt], f1, c, 0, 0, 0);
      union { __bf16 h4[4]; unsigned long long u; } pk;
#pragma unroll
      for (int e = 0; e < 4; ++e) {
        float v = c[e];
        v = (v > 0.f) ? v : (__expf(v) - 1.0f);
        pk.h4[e] = (__bf16)v;
      }
      if (live)
        *(unsigned long long*)(h_a + bcol * 264 + wid * 32 + tt * 16 + q * 4) = pk.u;
    }
    wg_barrier();

    // ---- phase B: wave-2 publishes z_eff(i+1) (WAR: 1 bar after reads; RAW:
    //      2 bars before next reads), then layer 2 ----
    if (zprod) {
      bool jmp = (tn_hold = t_g[i + 1], (tn_hold >= ev1));  // also load t(i+1)
      float2 zev = make_float2(jmp ? zjf.x : zpre.x, jmp ? zjf.y : zpre.y);
      *(float2*)(z_eff + m1 * 12 + d0) = zev;
    } else {
      tn_hold = t_g[i + 1];
    }
    layer(h_a, h_b, w2f, b2v);
    wg_barrier();

    // ---- phase C: layer 3 (-> h_a) + fused W4 partial on OWN 32 cols -> p4 ----
    layer(h_b, h_a, w3f, b3v);
    {
      if (live) h4r = ((const bf16x8*)h_a)[bcol * 33 + wid * 4 + q];  // same-wave RAW
      f32x4 c = {0.f, 0.f, 0.f, 0.f};
      c = __builtin_amdgcn_mfma_f32_16x16x32_bf16(w4f, h4r, c, 0, 0, 0);
      if (q < 2 && live)
        *(f32x4*)(p4 + wid * 128 + bcol * 8 + q * 4) = c;
    }
    wg_barrier();
  }
}

extern "C" void kernel_launch(void* const* d_in, const int* in_sizes, int n_in,
                              void* d_out, int out_size, void* d_ws, size_t ws_size,
                              hipStream_t stream) {
  const float* t  = (const float*)d_in[0];
  const float* x  = (const float*)d_in[1];
  const float* z  = (const float*)d_in[2];
  const float* ev = (const float*)d_in[3];
  const float* zj = (const float*)d_in[4];
  const float* W1 = (const float*)d_in[5];
  const float* b1 = (const float*)d_in[6];
  const float* W2 = (const float*)d_in[7];
  const float* b2 = (const float*)d_in[8];
  const float* W3 = (const float*)d_in[9];
  const float* b3 = (const float*)d_in[10];
  const float* W4 = (const float*)d_in[11];
  const float* b4 = (const float*)d_in[12];
  __bf16* ws = (__bf16*)d_ws;
  float* out = (float*)d_out;

  prep_weights<<<592, 256, 0, stream>>>(W1, b1, W2, W3, W4, ws);
  ode_main<<<256, 512, 0, stream>>>(t, x, z, ev, zj, b2, b3, b4, ws, out);
}

// Round 11
// 1809.582 us; speedup vs baseline: 1.9467x; 1.6061x over previous
//
#include <hip/hip_runtime.h>
#include <cstdint>
#include <cstddef>

typedef __bf16 bf16x8 __attribute__((ext_vector_type(8)));
typedef float f32x4 __attribute__((ext_vector_type(4)));

#define HD 256
#define TLEN 1000
#define NSTEP 999
#define BTILE 4

// ws layout (bf16 elements): W1R | W2R | W3R | W4R, fragment-ordered
#define W1R_OFF 0
#define W2R_OFF 16384
#define W3R_OFF 81920
#define W4R_OFF 147456
#define WS_ELEMS 151552

__device__ __forceinline__ void wg_barrier() {
  // LDS-only drain + barrier: do NOT force vmcnt(0) like __syncthreads does,
  // so the z-prefetch / out-stores stay in flight across layer barriers.
  asm volatile("s_waitcnt lgkmcnt(0)\n\ts_barrier" ::: "memory");
}

// Repack fp32 weights -> bf16 MFMA A-fragments in ws (r4 layout, unchanged).
// Fragment element for (w,kb,tt,lane,j): k = kb*32 + (lane>>4)*8 + j ; n = w*32 + tt*16 + (lane&15)
// value = W[k][n] (b1 folded into W1 padded row k==48).
__global__ void prep_weights(const float* __restrict__ W1, const float* __restrict__ b1,
                             const float* __restrict__ W2, const float* __restrict__ W3,
                             const float* __restrict__ W4, __bf16* __restrict__ ws) {
  int tid = blockIdx.x * blockDim.x + threadIdx.x;
  if (tid >= WS_ELEMS) return;
  float val = 0.0f;
  if (tid < W2R_OFF) {                       // W1R: 8w x 2kb x 2tt x 64lane x 8j
    int t = tid;
    int j = t & 7, lane = (t >> 3) & 63, tt = (t >> 9) & 1, kb = (t >> 10) & 1, w = (t >> 11) & 7;
    int k = kb * 32 + ((lane >> 4) * 8) + j;
    int n = w * 32 + tt * 16 + (lane & 15);
    if (k < 48) val = W1[k * HD + n];
    else if (k == 48) val = b1[n];           // bias folded via constant-1 input at k=48
  } else if (tid < W3R_OFF) {                // W2R: 8w x 8kb x 2tt x 64 x 8
    int t = tid - W2R_OFF;
    int j = t & 7, lane = (t >> 3) & 63, tt = (t >> 9) & 1, kb = (t >> 10) & 7, w = (t >> 13) & 7;
    int k = kb * 32 + ((lane >> 4) * 8) + j;
    int n = w * 32 + tt * 16 + (lane & 15);
    val = W2[k * HD + n];
  } else if (tid < W4R_OFF) {                // W3R
    int t = tid - W3R_OFF;
    int j = t & 7, lane = (t >> 3) & 63, tt = (t >> 9) & 1, kb = (t >> 10) & 7, w = (t >> 13) & 7;
    int k = kb * 32 + ((lane >> 4) * 8) + j;
    int n = w * 32 + tt * 16 + (lane & 15);
    val = W3[k * HD + n];
  } else {                                   // W4R: 8kb x 64 x 8, N padded 8->16 with zeros
    int t = tid - W4R_OFF;
    int j = t & 7, lane = (t >> 3) & 63, kb = (t >> 9) & 7;
    int k = kb * 32 + ((lane >> 4) * 8) + j;
    int n = lane & 15;
    val = (n < 8) ? W4[k * 8 + n] : 0.0f;
  }
  ws[tid] = (__bf16)val;
}

// r10 post-mortem: every structural add spills (256-reg/wave wall at 8 waves/CU;
// weights=148 resident). This version = r4 champion BYTE-IDENTICAL except ONE
// register-neutral change, tested in isolation:
//  (A) layer MFMA accumulation split 8-deep -> two independent 4-chains.
//      r4 arithmetic: MfmaUtil 30.9% x 3930cy = 1214 cy busy / 74 MFMA = 16.4
//      cy/MFMA = full dependent latency exposed. 4 chains/wave overlap the pipe.
//      Cost: +4 transient VGPRs inside the lambda only.
__global__ __launch_bounds__(512, 2) void ode_main(
    const float* __restrict__ t_g, const float* __restrict__ x_g,
    const float* __restrict__ z_g, const float* __restrict__ ev_g,
    const float* __restrict__ zj_g, const float* __restrict__ b2_g,
    const float* __restrict__ b3_g, const float* __restrict__ b4_g,
    const __bf16* __restrict__ ws, float* __restrict__ out) {
  __shared__ __align__(16) __bf16 h_a[16 * 264];   // 16 rows kept (4 live), row 528B
  __shared__ __align__(16) __bf16 h_b[16 * 264];
  __shared__ __align__(16) float p4[8 * 16 * 8];   // [wave][bcol][dim]
  __shared__ __align__(16) float x_cur[16 * 12];
  __shared__ __align__(16) float z_eff[16 * 12];
  __shared__ __align__(16) float x0s[16 * 12];
  __shared__ __align__(16) float z0s[16 * 12];
  __shared__ __align__(16) float zjs[16 * 12];
  __shared__ float evs[16];

  const int tid  = threadIdx.x;
  const int lane = tid & 63;
  const int wid  = tid >> 6;     // 8 waves; wave w owns hidden cols [32w, 32w+32)
  const int bcol = lane & 15;    // B/C-operand column; batch row if < BTILE, dead otherwise
  const int q    = lane >> 4;    // quad
  const int b0   = blockIdx.x * BTILE;
  const bool live = bcol < BTILE;

  // ---- stage per-batch constants (rows >= BTILE zeroed: dead cols stay exact 0) ----
  if (tid < 128) {
    int m = tid >> 3, d = tid & 7;
    if (m < BTILE) {
      size_t gb = (size_t)(b0 + m);
      float x0 = x_g[gb * (TLEN * 8) + d];
      float z0 = z_g[gb * (TLEN * 8) + d];
      x0s[m * 12 + d] = x0;
      z0s[m * 12 + d] = z0;
      x_cur[m * 12 + d] = x0;
      zjs[m * 12 + d] = zj_g[gb * 8 + d];
      out[gb * (TLEN * 8) + d] = x0;         // sol[:,0] = x0
      if (d == 0) evs[m] = ev_g[gb];
    } else {
      x0s[m * 12 + d] = 0.f;
      z0s[m * 12 + d] = 0.f;
      x_cur[m * 12 + d] = 0.f;
      zjs[m * 12 + d] = 0.f;
      if (d == 0) evs[m] = 0.f;
    }
  }
  __syncthreads();

  if (tid < 128) {  // z_eff for step 0 (rows >= BTILE resolve to 0)
    int m = tid >> 3, d = tid & 7;
    float t0 = t_g[0];
    z_eff[m * 12 + d] = (t0 >= evs[m]) ? zjs[m * 12 + d] : z0s[m * 12 + d];
  }

  // ---- resident weight fragments (A-operand layout) ----
  const bf16x8* wsv = (const bf16x8*)ws;
  bf16x8 w1f[2][2], w2f[8][2], w3f[8][2];
#pragma unroll
  for (int kb = 0; kb < 2; ++kb)
#pragma unroll
    for (int tt = 0; tt < 2; ++tt)
      w1f[kb][tt] = wsv[(W1R_OFF / 8) + ((wid * 2 + kb) * 2 + tt) * 64 + lane];
#pragma unroll
  for (int kb = 0; kb < 8; ++kb)
#pragma unroll
    for (int tt = 0; tt < 2; ++tt) {
      w2f[kb][tt] = wsv[(W2R_OFF / 8) + ((wid * 8 + kb) * 2 + tt) * 64 + lane];
      w3f[kb][tt] = wsv[(W3R_OFF / 8) + ((wid * 8 + kb) * 2 + tt) * 64 + lane];
    }
  // W4 k-slice for this wave: k in [32*wid, 32*wid+32)
  bf16x8 w4f = wsv[(W4R_OFF / 8) + wid * 64 + lane];

  // biases as C-init: lane's 4 C rows are hidden n = wid*32 + tt*16 + q*4 + e
  f32x4 b2v[2], b3v[2];
#pragma unroll
  for (int tt = 0; tt < 2; ++tt) {
    int n0 = wid * 32 + tt * 16 + q * 4;
    b2v[tt] = *(const f32x4*)(b2_g + n0);
    b3v[tt] = *(const f32x4*)(b3_g + n0);
  }
  float b4l = (tid < 64) ? b4_g[tid & 7] : 0.0f;

  // wave-2 personals (z_eff producer): lanes 0..BTILE*4-1 cover (m 0..BTILE-1) x (d pairs)
  const int m1 = lane >> 2;          // batch row
  const int d0 = (lane & 3) * 2;
  float2 zjf = make_float2(0.f, 0.f);
  float ev1 = 0.f;
  const bool zprod = (wid == 2) && (lane < BTILE * 4);
  if (zprod) {
    zjf.x = zjs[m1 * 12 + d0];
    zjf.y = zjs[m1 * 12 + d0 + 1];
    ev1 = evs[m1];
  }

  // layer-1 per-lane B-frag constants:
  // q=0: k=0..7   -> x0 (const)          q=1: k=8..15  -> z0 (const)
  // q=2: k=16..23 -> x_cur - x0          q=3: k=24..31 -> z_eff - z0
  f32x4 sub0, sub1;
  bf16x8 a0c;
  {
    const float* base = ((q & 1) ? z0s : x0s) + bcol * 12;
    f32x4 r0 = *(const f32x4*)(base);
    f32x4 r1 = *(const f32x4*)(base + 4);
    sub0 = r0; sub1 = r1;
#pragma unroll
    for (int e = 0; e < 4; ++e) { a0c[e] = (__bf16)r0[e]; a0c[e + 4] = (__bf16)r1[e]; }
  }
  bf16x8 zf;
#pragma unroll
  for (int e = 0; e < 8; ++e) zf[e] = (__bf16)0.f;
  bf16x8 k48f = zf;
  k48f[0] = (__bf16)1.0f;  // constant-1 input at padded k=48 -> adds b1

  __syncthreads();

  float tc = t_g[0];

  // persistent masked-read destinations: dead lanes keep zeros forever.
  bf16x8 bfr[8];
#pragma unroll
  for (int kb = 0; kb < 8; ++kb) bfr[kb] = zf;
  bf16x8 h4r = zf;

  auto layer = [&](const __bf16* src, __bf16* dst, const bf16x8 (*wf)[2], const f32x4* bv) {
    const bf16x8* hp = (const bf16x8*)src;
    if (live) {   // masked reads: dead lanes generate no LDS traffic
#pragma unroll
      for (int kb = 0; kb < 8; ++kb) bfr[kb] = hp[bcol * 33 + kb * 4 + q];  // ds_read_b128 x8
    }
#pragma unroll
    for (int tt = 0; tt < 2; ++tt) {
      f32x4 c0 = bv[tt];
      f32x4 c1 = {0.f, 0.f, 0.f, 0.f};
      // (A) two independent 4-chains per tt -> 4 chains in flight per wave
#pragma unroll
      for (int kb = 0; kb < 4; ++kb)
        c0 = __builtin_amdgcn_mfma_f32_16x16x32_bf16(wf[kb][tt], bfr[kb], c0, 0, 0, 0);
#pragma unroll
      for (int kb = 4; kb < 8; ++kb)
        c1 = __builtin_amdgcn_mfma_f32_16x16x32_bf16(wf[kb][tt], bfr[kb], c1, 0, 0, 0);
      union { __bf16 h4[4]; unsigned long long u; } pk;
#pragma unroll
      for (int e = 0; e < 4; ++e) {
        float v = c0[e] + c1[e];
        v = (v > 0.f) ? v : (__expf(v) - 1.0f);  // ELU
        pk.h4[e] = (__bf16)v;
      }
      // 4 consecutive hidden cols for batch bcol -> one ds_write_b64
      if (live)
        *(unsigned long long*)(dst + bcol * 264 + wid * 32 + tt * 16 + q * 4) = pk.u;
    }
  };

#pragma unroll 1
  for (int i = 0; i < NSTEP; ++i) {
    float tn = t_g[i + 1];
    float2 zpre = make_float2(0.f, 0.f);
    if (zprod)  // prefetch z[:, i+1]; consumed in phase 4 of this step
      zpre = *(const float2*)(z_g + ((size_t)(b0 + m1) * TLEN + (i + 1)) * 8 + d0);

    // ---- phase 1: layer 1 (K padded 48->64, bias via k=48) ----
    {
      const float* rp = ((q & 1) ? z_eff : x_cur) + bcol * 12;
      f32x4 r0 = *(const f32x4*)(rp);
      f32x4 r1 = *(const f32x4*)(rp + 4);
      bf16x8 f0, f1;
      if (q < 2) {
        f0 = a0c;
#pragma unroll
        for (int e = 0; e < 4; ++e) { f1[e] = (__bf16)r0[e]; f1[e + 4] = (__bf16)r1[e]; }
      } else {
#pragma unroll
        for (int e = 0; e < 4; ++e) {
          f0[e] = (__bf16)(r0[e] - sub0[e]);
          f0[e + 4] = (__bf16)(r1[e] - sub1[e]);
        }
        f1 = (q == 2) ? k48f : zf;
      }
#pragma unroll
      for (int tt = 0; tt < 2; ++tt) {
        f32x4 c = {0.f, 0.f, 0.f, 0.f};
        c = __builtin_amdgcn_mfma_f32_16x16x32_bf16(w1f[0][tt], f0, c, 0, 0, 0);
        c = __builtin_amdgcn_mfma_f32_16x16x32_bf16(w1f[1][tt], f1, c, 0, 0, 0);
        union { __bf16 h4[4]; unsigned long long u; } pk;
#pragma unroll
        for (int e = 0; e < 4; ++e) {
          float v = c[e];
          v = (v > 0.f) ? v : (__expf(v) - 1.0f);
          pk.h4[e] = (__bf16)v;
        }
        if (live)
          *(unsigned long long*)(h_a + bcol * 264 + wid * 32 + tt * 16 + q * 4) = pk.u;
      }
    }
    wg_barrier();
    layer(h_a, h_b, w2f, b2v);   // phase 2: layer 2
    wg_barrier();
    layer(h_b, h_a, w3f, b3v);   // phase 3: layer 3 (h3 -> h_a)

    // ---- phase 3b (fused, no barrier): layer-4 partial on OWN 32 columns ----
    {
      const bf16x8* hp = (const bf16x8*)h_a;
      if (live) h4r = hp[bcol * 33 + wid * 4 + q];
      f32x4 c = {0.f, 0.f, 0.f, 0.f};
      c = __builtin_amdgcn_mfma_f32_16x16x32_bf16(w4f, h4r, c, 0, 0, 0);
      if (q < 2 && live)  // valid out rows n = q*4+e < 8
        *(f32x4*)(p4 + wid * 128 + bcol * 8 + q * 4) = c;
    }
    wg_barrier();

    // ---- phase 4: reduce + Euler (wave 0, rows < BTILE), z_eff(i+1) (wave 2) ----
    float dt = tn - tc;
    if (tid < 64) {
      int m = tid >> 3, d = tid & 7;
      if (m < BTILE) {                 // live batch rows only; rows >= BTILE stay 0
        float s = b4l;
#pragma unroll
        for (int j = 0; j < 8; ++j) s += p4[j * 128 + m * 8 + d];
        float xn = x_cur[m * 12 + d] + dt * s;
        x_cur[m * 12 + d] = xn;
        out[(size_t)(b0 + m) * (TLEN * 8) + (size_t)(i + 1) * 8 + d] = xn;
      }
    } else if (zprod) {
      bool jmp = (tn >= ev1);
      float2 zev = make_float2(jmp ? zjf.x : zpre.x, jmp ? zjf.y : zpre.y);
      *(float2*)(z_eff + m1 * 12 + d0) = zev;
    }
    tc = tn;
    wg_barrier();
  }
}

extern "C" void kernel_launch(void* const* d_in, const int* in_sizes, int n_in,
                              void* d_out, int out_size, void* d_ws, size_t ws_size,
                              hipStream_t stream) {
  const float* t  = (const float*)d_in[0];
  const float* x  = (const float*)d_in[1];
  const float* z  = (const float*)d_in[2];
  const float* ev = (const float*)d_in[3];
  const float* zj = (const float*)d_in[4];
  const float* W1 = (const float*)d_in[5];
  const float* b1 = (const float*)d_in[6];
  const float* W2 = (const float*)d_in[7];
  const float* b2 = (const float*)d_in[8];
  const float* W3 = (const float*)d_in[9];
  const float* b3 = (const float*)d_in[10];
  const float* W4 = (const float*)d_in[11];
  const float* b4 = (const float*)d_in[12];
  __bf16* ws = (__bf16*)d_ws;
  float* out = (float*)d_out;

  prep_weights<<<592, 256, 0, stream>>>(W1, b1, W2, W3, W4, ws);
  ode_main<<<256, 512, 0, stream>>>(t, x, z, ev, zj, b2, b3, b4, ws, out);
}